// Round 9
// baseline (53.160 us; speedup 1.0000x reference)
//
#include <hip/hip_runtime.h>
#include <math.h>

#define NUM_MOE 64
#define DIM 64
#define CH 16            // float4 chunks per row
#define TOK 64           // tokens per block
#define NW 4             // waves per block
#define ET 8             // experts per inner pass (2 passes per wave)

typedef float f32x2 __attribute__((ext_vector_type(2)));
typedef float f32x4 __attribute__((ext_vector_type(4)));

// acc = x*w + acc, packed fp32 (VOP3P, full rate -> the 157 TF path).
// x,acc: VGPR pairs; w: SGPR pair (the single allowed scalar operand --
// preserves the scalar W path, no v_mov copies).
#define PKFMA(acc, xv, wv) \
    asm("v_pk_fma_f32 %0, %1, %2, %0" : "+v"(acc) : "v"(xv), "s"(wv))

// R8 structure (4-wave cooperative block, XOR-swizzled token-major LDS,
// scalar-path W, lane=token fold, LDS partial merge) with:
//  1. inline-asm v_pk_fma_f32 (R8's builtin float2 fma did NOT lower to it:
//     VALU busy-time matched the scalar-rate estimate)
//  2. packed partials: LDS 21504 -> 20480 B = exactly 8 blocks/CU (was 7)
__global__ __launch_bounds__(256)
void moe_router_kernel(const float* __restrict__ x,
                       const float* __restrict__ W,
                       float* __restrict__ out,
                       int ntok) {
    __shared__ f32x4 xs[TOK * CH];                   // 16384 B
    __shared__ f32x2 pmm[NW][TOK];                   //  2048 B (m1,m2)
    __shared__ float pzz[NW][TOK];                   //  1024 B (Z partial)
    __shared__ int   pii[NW][TOK];                   //  1024 B (i1 | i2<<8)

    const int tid    = threadIdx.x;
    const long tbase = (long)blockIdx.x * TOK;

    // ---- stage x: coalesced float4 loads -> contiguous-permuted writes ----
    {
        const f32x4* __restrict__ g4 = reinterpret_cast<const f32x4*>(x) + tbase * CH;
        #pragma unroll
        for (int j = 0; j < 4; ++j) {
            const int G  = tid + j * 256;            // 0..1023, coalesced read
            const int tk = G >> 4;                   // token in block
            const int c  = G & 15;                   // chunk
            const int Gc = (tbase + tk < ntok) ? G : (G & 15);  // tail clamp
            xs[tk * CH + (c ^ (tk & 7))] = g4[Gc];   // canonical write pattern
        }
    }
    __syncthreads();

    // ---- compute: wave wid owns experts [wid*16, wid*16+16) ----
    const int lane = tid & 63;                       // token in block
    const int wid  = __builtin_amdgcn_readfirstlane(tid >> 6);
    const f32x4* __restrict__ Wg =
        reinterpret_cast<const f32x4*>(W) + (size_t)wid * 16 * CH;  // SGPR base

    float m1 = -INFINITY, m2 = -INFINITY, Zp = 0.0f;
    int   i1 = 0, i2 = 0;

    #pragma unroll
    for (int p = 0; p < 2; ++p) {                    // two 8-expert passes
        f32x2 acc[ET];
        #pragma unroll
        for (int e = 0; e < ET; ++e) acc[e] = (f32x2){0.0f, 0.0f};

        #pragma unroll
        for (int k = 0; k < CH; ++k) {
            const f32x4 xk = xs[lane * CH + (k ^ (lane & 7))];  // ~free (2-way)
            const f32x2 xa = {xk.x, xk.y};           // aligned subreg pairs
            const f32x2 xb = {xk.z, xk.w};
            #pragma unroll
            for (int e = 0; e < ET; ++e) {
                // uniform addr -> s_load_dwordx4; pairs stay in SGPRs
                const f32x4 wv = Wg[(p * ET + e) * CH + k];
                const f32x2 wa = {wv.x, wv.y};
                const f32x2 wb = {wv.z, wv.w};
                PKFMA(acc[e], xa, wa);               // v_pk_fma_f32
                PKFMA(acc[e], xb, wb);
            }
        }
        // fold pass into running Z + exact top-2 (strict '>' + ascending
        // order => lowest index wins ties, matching lax.top_k)
        #pragma unroll
        for (int e = 0; e < ET; ++e) {
            const float v  = acc[e].x + acc[e].y;
            const int   ge = wid * 16 + p * ET + e;
            Zp += __expf(v);                         // logits ~N(0,1): no max-sub
            const bool b1 = v > m1;
            const bool b2 = v > m2;
            i2 = b1 ? i1 : (b2 ? ge : i2);
            m2 = b1 ? m1 : (b2 ? v : m2);
            i1 = b1 ? ge : i1;
            m1 = b1 ? v  : m1;
        }
    }

    // ---- publish per-wave partials (disjoint, ascending expert ranges) ----
    pmm[wid][lane] = (f32x2){m1, m2};
    pzz[wid][lane] = Zp;
    pii[wid][lane] = i1 | (i2 << 8);
    __syncthreads();

    // ---- merge + output: thread -> (token = tid>>2, quarter q = tid&3) ----
    {
        const int tk = tid >> 2;
        const int q  = tid & 3;

        f32x2 mm0 = pmm[0][tk];
        float M1 = mm0.x, M2 = mm0.y, Z = pzz[0][tk];
        int   pk0 = pii[0][tk];
        int   I1 = pk0 & 0xFF, I2 = pk0 >> 8;
        #pragma unroll
        for (int w = 1; w < NW; ++w) {
            const f32x2 mmw = pmm[w][tk];
            const float b1 = mmw.x, b2 = mmw.y;
            const int   pkw = pii[w][tk];
            const int   j1 = pkw & 0xFF, j2 = pkw >> 8;
            Z += pzz[w][tk];
            // w-range expert indices all higher than current -> strict '>'
            // keeps lowest-index-wins tie semantics exactly.
            const bool rep = b1 > M1;
            const float nm2 = rep ? ((b2 > M1) ? b2 : M1) : ((b1 > M2) ? b1 : M2);
            const int   ni2 = rep ? ((b2 > M1) ? j2 : I1) : ((b1 > M2) ? j1 : I2);
            M1 = rep ? b1 : M1;
            I1 = rep ? j1 : I1;
            M2 = nm2;  I2 = ni2;
        }

        // out[I1] = sigmoid((E1-E2)/Z), out[I2] = 1 - out[I1]
        const float E1  = __expf(M1), E2 = __expf(M2);
        const float d12 = (E1 - E2) / Z;
        const float w1  = 1.0f / (1.0f + __expf(-d12));
        const float w2  = 1.0f - w1;

        if (tbase + tk < ntok) {
            // one 64B line fully owned by one lane -> clean write-combining
            float4* __restrict__ o4 =
                reinterpret_cast<float4*>(out) + (tbase + tk) * CH + q * 4;
            #pragma unroll
            for (int kk = 0; kk < 4; ++kk) {
                const int j = q * 16 + kk * 4;
                float4 v;
                v.x = (j + 0 == I1) ? w1 : ((j + 0 == I2) ? w2 : 0.0f);
                v.y = (j + 1 == I1) ? w1 : ((j + 1 == I2) ? w2 : 0.0f);
                v.z = (j + 2 == I1) ? w1 : ((j + 2 == I2) ? w2 : 0.0f);
                v.w = (j + 3 == I1) ? w1 : ((j + 3 == I2) ? w2 : 0.0f);
                o4[kk] = v;
            }
        }
    }
}

extern "C" void kernel_launch(void* const* d_in, const int* in_sizes, int n_in,
                              void* d_out, int out_size, void* d_ws, size_t ws_size,
                              hipStream_t stream) {
    const float* x = (const float*)d_in[0];
    const float* W = (const float*)d_in[1];
    float* out = (float*)d_out;
    int ntok = in_sizes[0] / DIM;                    // 262144

    int blocks = (ntok + TOK - 1) / TOK;             // 4096
    moe_router_kernel<<<blocks, 256, 0, stream>>>(x, W, out, ntok);
}

// Round 10
// 42.279 us; speedup vs baseline: 1.2573x; 1.2573x over previous
//
#include <hip/hip_runtime.h>
#include <math.h>

#define NUM_MOE 64
#define DIM 64
#define CH 16            // float4 chunks per row
#define TOK 64           // tokens per block
#define NW 4             // waves per block
#define ET 8             // experts per inner pass (2 passes per wave)

typedef float f32x2 __attribute__((ext_vector_type(2)));
typedef float f32x4 __attribute__((ext_vector_type(4)));
typedef float f32x8 __attribute__((ext_vector_type(8)));

// R8 base (48us: 4-wave cooperative block, XOR-swizzled token-major LDS,
// scalar-path W, lane=token fold, LDS partial merge; builtin fma -- R9
// proved v_pk_fma_f32 asm is throughput-neutral and scheduled worse) plus:
//  1. W via f32x8 -> s_load_dwordx8: halves scalar-pipe instrs + lgkm
//     events per FMA (was 1 s_load per 2 FMA-pairs, the stall suspect)
//  2. epilogue: coalesced zero-fill issued BEFORE compute (latency hidden;
//     barrier's vmcnt(0) drain orders it), wave0 merges + scatters 2
//     dwords/token. Deletes ~128 cndmask VALU per thread.
__global__ __launch_bounds__(256)
void moe_router_kernel(const float* __restrict__ x,
                       const float* __restrict__ W,
                       float* __restrict__ out,
                       int ntok) {
    __shared__ f32x4 xs[TOK * CH];                   // 16384 B
    __shared__ float pm1[NW][TOK], pm2[NW][TOK], pz[NW][TOK];
    __shared__ int   pi1[NW][TOK], pi2[NW][TOK];     // total 21504 B -> 7 blk/CU

    const int tid    = threadIdx.x;
    const long tbase = (long)blockIdx.x * TOK;

    // ---- stage x (coalesced loads -> contiguous-permuted LDS writes) ----
    {
        const f32x4* __restrict__ g4 = reinterpret_cast<const f32x4*>(x) + tbase * CH;
        #pragma unroll
        for (int j = 0; j < 4; ++j) {
            const int G  = tid + j * 256;            // 0..1023, coalesced read
            const int tk = G >> 4;                   // token in block
            const int c  = G & 15;                   // chunk
            const int Gc = (tbase + tk < ntok) ? G : (G & 15);  // tail clamp
            xs[tk * CH + (c ^ (tk & 7))] = g4[Gc];   // canonical write pattern
        }
    }

    // ---- zero-fill output tile now; latency hides under compute. The
    // pre-compute barrier drains vmcnt -> all zeros complete before the
    // post-merge scatter can issue. ----
    {
        f32x4* __restrict__ ob = reinterpret_cast<f32x4*>(out) + tbase * CH;
        const f32x4 z4 = {0.0f, 0.0f, 0.0f, 0.0f};
        #pragma unroll
        for (int j = 0; j < 4; ++j) {
            const int F = tid + j * 256;             // 0..1023, coalesced
            if (tbase + (F >> 4) < ntok) ob[F] = z4;
        }
    }
    __syncthreads();

    // ---- compute: wave wid owns experts [wid*16, wid*16+16) ----
    const int lane = tid & 63;                       // token in block
    const int wid  = __builtin_amdgcn_readfirstlane(tid >> 6);
    // expert row = 8 f32x8 units; uniform base -> s_load_dwordx8 path
    const f32x8* __restrict__ Wg8 =
        reinterpret_cast<const f32x8*>(W) + (size_t)wid * 16 * (DIM / 8);

    float m1 = -INFINITY, m2 = -INFINITY, Zp = 0.0f;
    int   i1 = 0, i2 = 0;

    #pragma unroll
    for (int p = 0; p < 2; ++p) {                    // two 8-expert passes
        f32x2 acc[ET];
        #pragma unroll
        for (int e = 0; e < ET; ++e) acc[e] = (f32x2){0.0f, 0.0f};

        #pragma unroll
        for (int k8 = 0; k8 < 8; ++k8) {             // 8-dim groups
            const f32x4 xk0 = xs[lane * CH + ((2 * k8) ^ (lane & 7))];
            const f32x4 xk1 = xs[lane * CH + ((2 * k8 + 1) ^ (lane & 7))];
            const f32x2 xa = {xk0.x, xk0.y};
            const f32x2 xb = {xk0.z, xk0.w};
            const f32x2 xc = {xk1.x, xk1.y};
            const f32x2 xd = {xk1.z, xk1.w};
            #pragma unroll
            for (int e = 0; e < ET; ++e) {
                // uniform addr, compile-time offset -> one s_load_dwordx8
                const f32x8 w8 = Wg8[(p * ET + e) * (DIM / 8) + k8];
                const f32x2 wa = {w8[0], w8[1]};     // aligned SGPR subpairs
                const f32x2 wb = {w8[2], w8[3]};
                const f32x2 wc = {w8[4], w8[5]};
                const f32x2 wd = {w8[6], w8[7]};
                acc[e] = __builtin_elementwise_fma(xa, wa, acc[e]);
                acc[e] = __builtin_elementwise_fma(xb, wb, acc[e]);
                acc[e] = __builtin_elementwise_fma(xc, wc, acc[e]);
                acc[e] = __builtin_elementwise_fma(xd, wd, acc[e]);
            }
        }
        // fold pass into running Z + exact top-2 (strict '>' + ascending
        // order => lowest index wins ties, matching lax.top_k)
        #pragma unroll
        for (int e = 0; e < ET; ++e) {
            const float v  = acc[e].x + acc[e].y;
            const int   ge = wid * 16 + p * ET + e;
            Zp += __expf(v);                         // logits ~N(0,1): no max-sub
            const bool b1 = v > m1;
            const bool b2 = v > m2;
            i2 = b1 ? i1 : (b2 ? ge : i2);
            m2 = b1 ? m1 : (b2 ? v : m2);
            i1 = b1 ? ge : i1;
            m1 = b1 ? v  : m1;
        }
    }

    // ---- publish per-wave partials (disjoint, ascending expert ranges) ----
    pm1[wid][lane] = m1;  pm2[wid][lane] = m2;  pz[wid][lane] = Zp;
    pi1[wid][lane] = i1;  pi2[wid][lane] = i2;
    __syncthreads();

    // ---- wave 0 merges and scatters 2 dwords per token ----
    if (tid < 64) {
        const int tk = tid;                          // one token per lane
        float M1 = pm1[0][tk], M2 = pm2[0][tk], Z = pz[0][tk];
        int   I1 = pi1[0][tk], I2 = pi2[0][tk];
        #pragma unroll
        for (int w = 1; w < NW; ++w) {
            const float b1 = pm1[w][tk], b2 = pm2[w][tk];
            const int   j1 = pi1[w][tk], j2 = pi2[w][tk];
            Z += pz[w][tk];
            // w-range expert indices all higher than current -> strict '>'
            // keeps lowest-index-wins tie semantics exactly.
            const bool rep = b1 > M1;
            const float nm2 = rep ? ((b2 > M1) ? b2 : M1) : ((b1 > M2) ? b1 : M2);
            const int   ni2 = rep ? ((b2 > M1) ? j2 : I1) : ((b1 > M2) ? j1 : I2);
            M1 = rep ? b1 : M1;
            I1 = rep ? j1 : I1;
            M2 = nm2;  I2 = ni2;
        }

        // out[I1] = sigmoid((E1-E2)/Z), out[I2] = 1 - out[I1]
        const float E1  = __expf(M1), E2 = __expf(M2);
        const float d12 = (E1 - E2) / Z;
        const float w1  = 1.0f / (1.0f + __expf(-d12));
        const float w2  = 1.0f - w1;

        if (tbase + tk < ntok) {
            float* __restrict__ orow = out + (tbase + tk) * DIM;
            orow[I1] = w1;                           // zeros already landed
            orow[I2] = w2;                           // (ordered by barrier)
        }
    }
}

extern "C" void kernel_launch(void* const* d_in, const int* in_sizes, int n_in,
                              void* d_out, int out_size, void* d_ws, size_t ws_size,
                              hipStream_t stream) {
    const float* x = (const float*)d_in[0];
    const float* W = (const float*)d_in[1];
    float* out = (float*)d_out;
    int ntok = in_sizes[0] / DIM;                    // 262144

    int blocks = (ntok + TOK - 1) / TOK;             // 4096
    moe_router_kernel<<<blocks, 256, 0, stream>>>(x, W, out, ntok);
}